// Round 4
// baseline (416.721 us; speedup 1.0000x reference)
//
#include <hip/hip_runtime.h>
#include <math.h>

#define Nn 32
#define Cc 64
#define Tt 128
#define Vv 25
#define Kk 204800   // C*T*V
#define Hh 256
#define Ee 4
#define KC 256
#define NBLK_A 800  // Kk / KC

__device__ __forceinline__ float elu1(float v) { return v > 0.0f ? v : expm1f(v); }

typedef const __attribute__((address_space(1))) void* gvp;
typedef __attribute__((address_space(3))) void* lvp;
// async DMA global->LDS, 16B per lane, lands at ldsbase + lane*16
__device__ __forceinline__ void gl_lds16(const void* g, void* l) {
  __builtin_amdgcn_global_load_lds((gvp)g, (lvp)l, 16, 0, 0);
}

// ---------------- Kernel A: split-K  partials[b][n][h] = sum_{k in chunk b} x[n,k]*W0[k,h]
// 800 blocks x 256 thr. LDS: xs 32KB only -> 3 blocks/CU (launch_bounds(256,3)), 12 waves/CU.
// W0: global->VGPR with explicit register ping-pong (depth-1 software pipeline),
// no barriers in the k-loop. x: LDS broadcast reads.
struct WGrp { float4 a[4]; float4 b[4]; };   // 4 k-rows x 8 h-cols

__global__ __launch_bounds__(256, 3) void kA(const float* __restrict__ x,
                                             const float* __restrict__ W0,
                                             float* __restrict__ partials) {
  __shared__ float xs[Nn][KC];        // 32 KB
  const int tid  = threadIdx.x;
  const int lane = tid & 63;
  const int wv   = tid >> 6;
  const int b  = blockIdx.x;
  const int k0 = b * KC;

  // async-stage x[0:32, k0:k0+256): 32 rows x 1KB, one DMA instr per row per wave-slice
  for (int r = wv; r < Nn; r += 4)
    gl_lds16(x + (size_t)r * Kk + k0 + lane * 4, &xs[r][0]);

  const int hg = tid & 31;   // h0 = hg*8
  const int np = tid >> 5;   // n0 = np*4
  const int h0 = hg * 8;
  const int n0 = np * 4;
  const float* W0p = W0 + (size_t)k0 * Hh + h0;

  float acc[4][8];
  #pragma unroll
  for (int i = 0; i < 4; ++i)
    #pragma unroll
    for (int c = 0; c < 8; ++c) acc[i][c] = 0.0f;

  WGrp g0, g1;
  // prefetch group 0 (k rows 0..3) while the x DMA is still in flight
  #pragma unroll
  for (int u = 0; u < 4; ++u) {
    const float* wp = W0p + (size_t)u * Hh;
    g0.a[u] = *(const float4*)(wp);
    g0.b[u] = *(const float4*)(wp + 4);
  }
  __syncthreads();   // xs ready

  #pragma unroll 1
  for (int kk = 0; kk < KC; kk += 8) {
    // ---- issue loads for group g1 (rows kk+4..kk+7) ----
    #pragma unroll
    for (int u = 0; u < 4; ++u) {
      const float* wp = W0p + (size_t)(kk + 4 + u) * Hh;
      g1.a[u] = *(const float4*)(wp);
      g1.b[u] = *(const float4*)(wp + 4);
    }
    // ---- FMA with g0 (rows kk..kk+3) ----
    {
      float4 xv[4];
      #pragma unroll
      for (int i = 0; i < 4; ++i)
        xv[i] = *(const float4*)&xs[n0 + i][kk];   // 2-address broadcast
      #pragma unroll
      for (int u = 0; u < 4; ++u) {
        float4 wa = g0.a[u], wb = g0.b[u];
        #pragma unroll
        for (int i = 0; i < 4; ++i) {
          float xu = (u == 0) ? xv[i].x : (u == 1) ? xv[i].y : (u == 2) ? xv[i].z : xv[i].w;
          acc[i][0] = fmaf(xu, wa.x, acc[i][0]);
          acc[i][1] = fmaf(xu, wa.y, acc[i][1]);
          acc[i][2] = fmaf(xu, wa.z, acc[i][2]);
          acc[i][3] = fmaf(xu, wa.w, acc[i][3]);
          acc[i][4] = fmaf(xu, wb.x, acc[i][4]);
          acc[i][5] = fmaf(xu, wb.y, acc[i][5]);
          acc[i][6] = fmaf(xu, wb.z, acc[i][6]);
          acc[i][7] = fmaf(xu, wb.w, acc[i][7]);
        }
      }
    }
    // ---- issue loads for next g0 (rows kk+8..kk+11); dead on last iter ----
    {
      const int nk = (kk + 8 < KC) ? (kk + 8) : 0;
      #pragma unroll
      for (int u = 0; u < 4; ++u) {
        const float* wp = W0p + (size_t)(nk + u) * Hh;
        g0.a[u] = *(const float4*)(wp);
        g0.b[u] = *(const float4*)(wp + 4);
      }
    }
    // ---- FMA with g1 (rows kk+4..kk+7) ----
    {
      float4 xv[4];
      #pragma unroll
      for (int i = 0; i < 4; ++i)
        xv[i] = *(const float4*)&xs[n0 + i][kk + 4];
      #pragma unroll
      for (int u = 0; u < 4; ++u) {
        float4 wa = g1.a[u], wb = g1.b[u];
        #pragma unroll
        for (int i = 0; i < 4; ++i) {
          float xu = (u == 0) ? xv[i].x : (u == 1) ? xv[i].y : (u == 2) ? xv[i].z : xv[i].w;
          acc[i][0] = fmaf(xu, wa.x, acc[i][0]);
          acc[i][1] = fmaf(xu, wa.y, acc[i][1]);
          acc[i][2] = fmaf(xu, wa.z, acc[i][2]);
          acc[i][3] = fmaf(xu, wa.w, acc[i][3]);
          acc[i][4] = fmaf(xu, wb.x, acc[i][4]);
          acc[i][5] = fmaf(xu, wb.y, acc[i][5]);
          acc[i][6] = fmaf(xu, wb.z, acc[i][6]);
          acc[i][7] = fmaf(xu, wb.w, acc[i][7]);
        }
      }
    }
  }

  #pragma unroll
  for (int i = 0; i < 4; ++i) {
    float* pp = partials + ((size_t)(b * Nn + n0 + i) << 8) + h0;
    *(float4*)(pp)     = make_float4(acc[i][0], acc[i][1], acc[i][2], acc[i][3]);
    *(float4*)(pp + 4) = make_float4(acc[i][4], acc[i][5], acc[i][6], acc[i][7]);
  }
}

// ---------------- Kernel B1: reduce 800 partials, + b0, ELU  -> hb[n][h]
__global__ __launch_bounds__(256) void kB1(const float* __restrict__ partials,
                                           const float* __restrict__ b0,
                                           float* __restrict__ hb) {
  const int n  = blockIdx.x >> 3;
  const int hc = blockIdx.x & 7;
  const int tid = threadIdx.x;
  const int hl = tid & 31;
  const int bsub = tid >> 5;     // 8 sub-reducers x 100 each
  const int h = hc * 32 + hl;
  float s = 0.0f;
  for (int j = 0; j < 100; ++j) {
    int b = bsub * 100 + j;
    s += partials[((size_t)(b * Nn + n) << 8) + h];
  }
  __shared__ float red[8][32];
  red[bsub][hl] = s;
  __syncthreads();
  if (tid < 32) {
    float tot = 0.0f;
    #pragma unroll
    for (int sI = 0; sI < 8; ++sI) tot += red[sI][tid];
    int hh = hc * 32 + tid;
    hb[n * Hh + hh] = elu1(tot + b0[hh]);
  }
}

// ---------------- Kernel B2: h2 = elu(hb@W1+b1); logits = h2@W2+b2; softmax -> wgt[n][e]
__global__ __launch_bounds__(256) void kB2(const float* __restrict__ hb,
                                           const float* __restrict__ W1,
                                           const float* __restrict__ b1,
                                           const float* __restrict__ W2,
                                           const float* __restrict__ b2,
                                           float* __restrict__ wgt) {
  const int n = blockIdx.x;
  const int tid = threadIdx.x;
  __shared__ float hbs[Hh];
  hbs[tid] = hb[n * Hh + tid];
  __syncthreads();
  float s = b1[tid];
  for (int j = 0; j < Hh; ++j) s = fmaf(hbs[j], W1[j * Hh + tid], s);
  float h2 = elu1(s);
  float le[Ee];
  #pragma unroll
  for (int e = 0; e < Ee; ++e) le[e] = h2 * W2[tid * Ee + e];
  __shared__ float red[Ee][4];
  const int lane = tid & 63;
  const int wid  = tid >> 6;
  #pragma unroll
  for (int e = 0; e < Ee; ++e) {
    float v = le[e];
    for (int off = 32; off > 0; off >>= 1) v += __shfl_down(v, off, 64);
    if (lane == 0) red[e][wid] = v;
  }
  __syncthreads();
  if (tid == 0) {
    float lg[Ee];
    float m = -1e30f;
    #pragma unroll
    for (int e = 0; e < Ee; ++e) {
      lg[e] = red[e][0] + red[e][1] + red[e][2] + red[e][3] + b2[e];
      m = fmaxf(m, lg[e]);
    }
    float den = 0.0f;
    #pragma unroll
    for (int e = 0; e < Ee; ++e) { lg[e] = expf(lg[e] - m); den += lg[e]; }
    float inv = 1.0f / den;
    #pragma unroll
    for (int e = 0; e < Ee; ++e) wgt[n * Ee + e] = lg[e] * inv;
  }
}

// ---------------- Kernel C: per (n,t): AS[v][w] = sum_e wgt[n][e]*A[e][t][v][w];
//                  out[n][c][t][w] = sum_v x[n][c][t][v] * AS[v][w]
#define ASW 28   // padded AS row
#define XTS 68   // padded xT row
__global__ __launch_bounds__(256) void kC(const float* __restrict__ x,
                                          const float* __restrict__ A,
                                          const float* __restrict__ wgt,
                                          float* __restrict__ out) {
  const int blk = blockIdx.x;
  const int n  = blk >> 6;       // 32 n
  const int tp = blk & 63;       // 64 t-pairs
  const int tid = threadIdx.x;
  const int tsub = tid >> 7;     // which t of the pair
  const int tl = tid & 127;
  const int t = tp * 2 + tsub;

  __shared__ float AS[2][Vv][ASW];
  __shared__ float xT[2][Vv][XTS];

  float wv[Ee];
  #pragma unroll
  for (int e = 0; e < Ee; ++e) wv[e] = wgt[n * Ee + e];

  for (int idx = tl; idx < Vv * ASW; idx += 128) {
    int v = idx / ASW;
    int w = idx - v * ASW;
    float s = 0.0f;
    if (w < Vv) {
      #pragma unroll
      for (int e = 0; e < Ee; ++e)
        s = fmaf(wv[e], A[((size_t)(e * Tt + t) * Vv + v) * Vv + w], s);
    }
    AS[tsub][v][w] = s;
  }
  const float* xb = x + (size_t)n * (Cc * Tt * Vv) + (size_t)t * Vv;
  for (int idx = tl; idx < Cc * Vv; idx += 128) {
    int c = idx / Vv;
    int v = idx - c * Vv;
    xT[tsub][v][c] = xb[(size_t)c * (Tt * Vv) + v];
  }
  __syncthreads();

  const int ct = tl & 15;        // c0 = ct*4
  const int wq = tl >> 4;        // 0..7, active if <7
  if (wq < 7) {
    const int c0 = ct * 4;
    const int w0 = wq * 4;
    float acc[4][4];
    #pragma unroll
    for (int i = 0; i < 4; ++i)
      #pragma unroll
      for (int j = 0; j < 4; ++j) acc[i][j] = 0.0f;
    #pragma unroll 5
    for (int v = 0; v < Vv; ++v) {
      float4 a4 = *(const float4*)&AS[tsub][v][w0];
      float4 x4 = *(const float4*)&xT[tsub][v][c0];
      const float xr[4] = {x4.x, x4.y, x4.z, x4.w};
      const float ar[4] = {a4.x, a4.y, a4.z, a4.w};
      #pragma unroll
      for (int i = 0; i < 4; ++i)
        #pragma unroll
        for (int j = 0; j < 4; ++j)
          acc[i][j] = fmaf(xr[i], ar[j], acc[i][j]);
    }
    #pragma unroll
    for (int i = 0; i < 4; ++i) {
      int c = c0 + i;
      float* ob = out + ((size_t)(n * Cc + c) * Tt + t) * Vv;
      #pragma unroll
      for (int j = 0; j < 4; ++j) {
        int w = w0 + j;
        if (w < Vv) ob[w] = acc[i][j];
      }
    }
  }
}

extern "C" void kernel_launch(void* const* d_in, const int* in_sizes, int n_in,
                              void* d_out, int out_size, void* d_ws, size_t ws_size,
                              hipStream_t stream) {
  const float* x  = (const float*)d_in[0];
  const float* W0 = (const float*)d_in[1];
  const float* b0 = (const float*)d_in[2];
  const float* W1 = (const float*)d_in[3];
  const float* b1 = (const float*)d_in[4];
  const float* W2 = (const float*)d_in[5];
  const float* b2 = (const float*)d_in[6];
  const float* A  = (const float*)d_in[7];
  float* out = (float*)d_out;

  float* partials = (float*)d_ws;                          // 800*32*256 floats = 26.2 MB
  float* hb  = partials + (size_t)NBLK_A * Nn * Hh;        // 8192 floats
  float* wgt = hb + Nn * Hh;                               // 128 floats

  kA <<<NBLK_A,  256, 0, stream>>>(x, W0, partials);
  kB1<<<256,     256, 0, stream>>>(partials, b0, hb);
  kB2<<<Nn,      256, 0, stream>>>(hb, W1, b1, W2, b2, wgt);
  kC <<<Nn * 64, 256, 0, stream>>>(x, A, wgt, out);
}

// Round 6
// 408.957 us; speedup vs baseline: 1.0190x; 1.0190x over previous
//
#include <hip/hip_runtime.h>
#include <math.h>

#define Nn 32
#define Cc 64
#define Tt 128
#define Vv 25
#define Kk 204800   // C*T*V
#define Hh 256
#define Ee 4
#define KC 128
#define NBLK_A 1600  // Kk / KC

__device__ __forceinline__ float elu1(float v) { return v > 0.0f ? v : expm1f(v); }

typedef const __attribute__((address_space(1))) void* gvp;
typedef __attribute__((address_space(3))) void* lvp;
__device__ __forceinline__ void gl_lds16(const void* g, void* l) {
  __builtin_amdgcn_global_load_lds((gvp)g, (lvp)l, 16, 0, 0);
}

typedef float v4f __attribute__((ext_vector_type(4)));

// ---------------- Kernel A: split-K  partials[b][n][h] = sum_{k in chunk b} x[n,k]*W0[k,h]
// 1600 blocks x 256 thr (KC=128). LDS 16KB -> high blocks/CU; TLP hides latency.
// Thread tile 8n x 4h: h0 = lane*4 so one dwordx4 per W0 row = 1KB unique, no lane dup.
__global__ __launch_bounds__(256) void kA(const float* __restrict__ x,
                                          const float* __restrict__ W0,
                                          float* __restrict__ partials) {
  __shared__ float xs[Nn][KC];        // 16 KB
  const int tid  = threadIdx.x;
  const int lane = tid & 63;
  const int wv   = tid >> 6;
  const int b  = blockIdx.x;
  const int k0 = b * KC;

  // stage x[0:32, k0:k0+128): rows are 512B; one 1KB DMA covers 2 rows.
  for (int rp = wv; rp < 16; rp += 4) {
    const int row = 2 * rp + (lane >> 5);
    gl_lds16(x + (size_t)row * Kk + k0 + (lane & 31) * 4, &xs[2 * rp][0]);
  }

  const int h0 = lane * 4;        // 64 lanes cover all 256 h
  const int n0 = wv * 8;          // 4 waves cover 32 n
  const float* W0p = W0 + (size_t)k0 * Hh + h0;

  float acc[8][4];
  #pragma unroll
  for (int i = 0; i < 8; ++i)
    #pragma unroll
    for (int c = 0; c < 4; ++c) acc[i][c] = 0.0f;

  __syncthreads();   // xs ready

  #pragma unroll 2
  for (int kk = 0; kk < KC; kk += 4) {
    v4f wr[4];
    #pragma unroll
    for (int u = 0; u < 4; ++u)
      wr[u] = *(const v4f*)(W0p + (size_t)(kk + u) * Hh);   // 1KB unique/wave
    v4f xv[8];
    #pragma unroll
    for (int i = 0; i < 8; ++i)
      xv[i] = *(const v4f*)&xs[n0 + i][kk];                 // wave-uniform broadcast b128
    #pragma unroll
    for (int u = 0; u < 4; ++u)
      #pragma unroll
      for (int i = 0; i < 8; ++i) {
        float xu = xv[i][u];
        acc[i][0] = fmaf(xu, wr[u][0], acc[i][0]);
        acc[i][1] = fmaf(xu, wr[u][1], acc[i][1]);
        acc[i][2] = fmaf(xu, wr[u][2], acc[i][2]);
        acc[i][3] = fmaf(xu, wr[u][3], acc[i][3]);
      }
  }

  #pragma unroll
  for (int i = 0; i < 8; ++i)
    *(v4f*)&partials[((size_t)(b * Nn + n0 + i) << 8) + h0] =
        (v4f){acc[i][0], acc[i][1], acc[i][2], acc[i][3]};
}

// ---------------- Kernel B1: reduce 1600 partials, + b0, ELU  -> hb[n][h]
__global__ __launch_bounds__(256) void kB1(const float* __restrict__ partials,
                                           const float* __restrict__ b0,
                                           float* __restrict__ hb) {
  const int n  = blockIdx.x >> 3;
  const int hc = blockIdx.x & 7;
  const int tid = threadIdx.x;
  const int hl = tid & 31;
  const int bsub = tid >> 5;     // 8 sub-reducers x 200 each
  const int h = hc * 32 + hl;
  float s = 0.0f;
  for (int j = 0; j < 200; ++j) {
    int b = bsub * 200 + j;
    s += partials[((size_t)(b * Nn + n) << 8) + h];
  }
  __shared__ float red[8][32];
  red[bsub][hl] = s;
  __syncthreads();
  if (tid < 32) {
    float tot = 0.0f;
    #pragma unroll
    for (int sI = 0; sI < 8; ++sI) tot += red[sI][tid];
    int hh = hc * 32 + tid;
    hb[n * Hh + hh] = elu1(tot + b0[hh]);
  }
}

// ---------------- Kernel B2: h2 = elu(hb@W1+b1); logits = h2@W2+b2; softmax -> wgt[n][e]
__global__ __launch_bounds__(256) void kB2(const float* __restrict__ hb,
                                           const float* __restrict__ W1,
                                           const float* __restrict__ b1,
                                           const float* __restrict__ W2,
                                           const float* __restrict__ b2,
                                           float* __restrict__ wgt) {
  const int n = blockIdx.x;
  const int tid = threadIdx.x;
  __shared__ float hbs[Hh];
  hbs[tid] = hb[n * Hh + tid];
  __syncthreads();
  float s = b1[tid];
  for (int j = 0; j < Hh; ++j) s = fmaf(hbs[j], W1[j * Hh + tid], s);
  float h2 = elu1(s);
  float le[Ee];
  #pragma unroll
  for (int e = 0; e < Ee; ++e) le[e] = h2 * W2[tid * Ee + e];
  __shared__ float red[Ee][4];
  const int lane = tid & 63;
  const int wid  = tid >> 6;
  #pragma unroll
  for (int e = 0; e < Ee; ++e) {
    float v = le[e];
    for (int off = 32; off > 0; off >>= 1) v += __shfl_down(v, off, 64);
    if (lane == 0) red[e][wid] = v;
  }
  __syncthreads();
  if (tid == 0) {
    float lg[Ee];
    float m = -1e30f;
    #pragma unroll
    for (int e = 0; e < Ee; ++e) {
      lg[e] = red[e][0] + red[e][1] + red[e][2] + red[e][3] + b2[e];
      m = fmaxf(m, lg[e]);
    }
    float den = 0.0f;
    #pragma unroll
    for (int e = 0; e < Ee; ++e) { lg[e] = expf(lg[e] - m); den += lg[e]; }
    float inv = 1.0f / den;
    #pragma unroll
    for (int e = 0; e < Ee; ++e) wgt[n * Ee + e] = lg[e] * inv;
  }
}

// ---------------- Kernel C: per (n,t): AS[v][w] = sum_e wgt[n][e]*A[e][t][v][w];
//                  out[n][c][t][w] = sum_v x[n][c][t][v] * AS[v][w]
#define ASW 28   // padded AS row
#define XTS 68   // padded xT row
__global__ __launch_bounds__(256) void kC(const float* __restrict__ x,
                                          const float* __restrict__ A,
                                          const float* __restrict__ wgt,
                                          float* __restrict__ out) {
  const int blk = blockIdx.x;
  const int n  = blk >> 6;       // 32 n
  const int tp = blk & 63;       // 64 t-pairs
  const int tid = threadIdx.x;
  const int tsub = tid >> 7;     // which t of the pair
  const int tl = tid & 127;
  const int t = tp * 2 + tsub;

  __shared__ float AS[2][Vv][ASW];
  __shared__ float xT[2][Vv][XTS];

  float wv[Ee];
  #pragma unroll
  for (int e = 0; e < Ee; ++e) wv[e] = wgt[n * Ee + e];

  for (int idx = tl; idx < Vv * ASW; idx += 128) {
    int v = idx / ASW;
    int w = idx - v * ASW;
    float s = 0.0f;
    if (w < Vv) {
      #pragma unroll
      for (int e = 0; e < Ee; ++e)
        s = fmaf(wv[e], A[((size_t)(e * Tt + t) * Vv + v) * Vv + w], s);
    }
    AS[tsub][v][w] = s;
  }
  const float* xb = x + (size_t)n * (Cc * Tt * Vv) + (size_t)t * Vv;
  for (int idx = tl; idx < Cc * Vv; idx += 128) {
    int c = idx / Vv;
    int v = idx - c * Vv;
    xT[tsub][v][c] = xb[(size_t)c * (Tt * Vv) + v];
  }
  __syncthreads();

  const int ct = tl & 15;        // c0 = ct*4
  const int wq = tl >> 4;        // 0..7, active if <7
  if (wq < 7) {
    const int c0 = ct * 4;
    const int w0 = wq * 4;
    float acc[4][4];
    #pragma unroll
    for (int i = 0; i < 4; ++i)
      #pragma unroll
      for (int j = 0; j < 4; ++j) acc[i][j] = 0.0f;
    #pragma unroll 5
    for (int v = 0; v < Vv; ++v) {
      float4 a4 = *(const float4*)&AS[tsub][v][w0];
      float4 x4 = *(const float4*)&xT[tsub][v][c0];
      const float xr[4] = {x4.x, x4.y, x4.z, x4.w};
      const float ar[4] = {a4.x, a4.y, a4.z, a4.w};
      #pragma unroll
      for (int i = 0; i < 4; ++i)
        #pragma unroll
        for (int j = 0; j < 4; ++j)
          acc[i][j] = fmaf(xr[i], ar[j], acc[i][j]);
    }
    #pragma unroll
    for (int i = 0; i < 4; ++i) {
      int c = c0 + i;
      float* ob = out + ((size_t)(n * Cc + c) * Tt + t) * Vv;
      #pragma unroll
      for (int j = 0; j < 4; ++j) {
        int w = w0 + j;
        if (w < Vv) ob[w] = acc[i][j];
      }
    }
  }
}

extern "C" void kernel_launch(void* const* d_in, const int* in_sizes, int n_in,
                              void* d_out, int out_size, void* d_ws, size_t ws_size,
                              hipStream_t stream) {
  const float* x  = (const float*)d_in[0];
  const float* W0 = (const float*)d_in[1];
  const float* b0 = (const float*)d_in[2];
  const float* W1 = (const float*)d_in[3];
  const float* b1 = (const float*)d_in[4];
  const float* W2 = (const float*)d_in[5];
  const float* b2 = (const float*)d_in[6];
  const float* A  = (const float*)d_in[7];
  float* out = (float*)d_out;

  float* partials = (float*)d_ws;                          // 1600*32*256 floats = 52.4 MB
  float* hb  = partials + (size_t)NBLK_A * Nn * Hh;        // 8192 floats
  float* wgt = hb + Nn * Hh;                               // 128 floats

  kA <<<NBLK_A,  256, 0, stream>>>(x, W0, partials);
  kB1<<<256,     256, 0, stream>>>(partials, b0, hb);
  kB2<<<Nn,      256, 0, stream>>>(hb, W1, b1, W2, b2, wgt);
  kC <<<Nn * 64, 256, 0, stream>>>(x, A, wgt, out);
}

// Round 7
// 389.550 us; speedup vs baseline: 1.0697x; 1.0498x over previous
//
#include <hip/hip_runtime.h>
#include <math.h>

#define Nn 32
#define Cc 64
#define Tt 128
#define Vv 25
#define Kk 204800   // C*T*V
#define Hh 256
#define Ee 4
#define KC 128
#define NBLK_A 1600  // Kk / KC

__device__ __forceinline__ float elu1(float v) { return v > 0.0f ? v : expm1f(v); }

typedef const __attribute__((address_space(1))) void* gvp;
typedef __attribute__((address_space(3))) void* lvp;
__device__ __forceinline__ void gl_lds16(const void* g, void* l) {
  __builtin_amdgcn_global_load_lds((gvp)g, (lvp)l, 16, 0, 0);
}

typedef float v4f __attribute__((ext_vector_type(4)));
typedef float v2f __attribute__((ext_vector_type(2)));

// ---------------- Kernel A: split-K  partials[b][n][h] = sum_{k in chunk b} x[n,k]*W0[k,h]
// 1600 blocks x 256 thr (KC=128). Wave = (k-slice, h-half): W0 chunk read EXACTLY ONCE
// per block (no intra-block duplication -> minimal bytes through L1, the measured
// ~12 B/cyc/CU delivery ceiling). Each wave covers all 32 n: float2 acc[32].
// Block reduce over the 2 k-slices via LDS (aliased over xs).
__global__ __launch_bounds__(256) void kA(const float* __restrict__ x,
                                          const float* __restrict__ W0,
                                          float* __restrict__ partials) {
  __shared__ float smem[Nn * Hh];            // 32 KB; [0,16KB)=xs, whole=red
  float (*xs)[KC] = (float(*)[KC])smem;      // [32][128]
  float (*red)[Hh] = (float(*)[Hh])smem;     // [32][256]

  const int tid  = threadIdx.x;
  const int lane = tid & 63;
  const int wv   = tid >> 6;       // 0..3
  const int slice = wv & 1;        // k-slice: rows [64*slice, 64*slice+64)
  const int half  = wv >> 1;       // h-half
  const int b  = blockIdx.x;
  const int k0 = b * KC;

  // stage x[0:32, k0:k0+128): rows are 512B; one 1KB DMA covers 2 rows.
  for (int rp = wv; rp < 16; rp += 4) {
    const int row = 2 * rp + (lane >> 5);
    gl_lds16(x + (size_t)row * Kk + k0 + (lane & 31) * 4, &xs[2 * rp][0]);
  }

  const int h0 = half * 128 + lane * 2;     // 2 h per lane
  const int ks = slice * 64;
  const float* W0p = W0 + ((size_t)k0 + ks) * Hh + h0;

  v2f acc[Nn];
  #pragma unroll
  for (int n = 0; n < Nn; ++n) acc[n] = (v2f){0.0f, 0.0f};

  __syncthreads();   // xs ready

  #pragma unroll 1
  for (int kk = 0; kk < 64; kk += 4) {
    v2f wr[4];
    #pragma unroll
    for (int u = 0; u < 4; ++u)
      wr[u] = *(const v2f*)(W0p + (size_t)(kk + u) * Hh);  // 512B/wave, unique
    #pragma unroll
    for (int n = 0; n < Nn; ++n) {
      v4f xv = *(const v4f*)&xs[n][ks + kk];               // broadcast b128
      #pragma unroll
      for (int u = 0; u < 4; ++u) {
        acc[n][0] = fmaf(xv[u], wr[u][0], acc[n][0]);
        acc[n][1] = fmaf(xv[u], wr[u][1], acc[n][1]);
      }
    }
  }

  // ---- block reduce over the 2 k-slices (columns are wave-exclusive per pass) ----
  __syncthreads();   // everyone done reading xs (red aliases it)
  if (slice == 0) {
    #pragma unroll
    for (int n = 0; n < Nn; ++n) *(v2f*)&red[n][h0] = acc[n];
  }
  __syncthreads();
  if (slice == 1) {
    #pragma unroll
    for (int n = 0; n < Nn; ++n) {
      v2f r = *(v2f*)&red[n][h0];
      r[0] += acc[n][0]; r[1] += acc[n][1];
      *(v2f*)&red[n][h0] = r;
    }
  }
  __syncthreads();

  // cooperative contiguous store: red flat [n][h] == partials[b] flat layout
  float* pb = partials + (size_t)b * (Nn * Hh);
  #pragma unroll
  for (int j = tid; j < (Nn * Hh) / 4; j += 256)
    *(float4*)&pb[j * 4] = *(const float4*)&smem[j * 4];
}

// ---------------- Kernel B1: reduce 1600 partials, + b0, ELU  -> hb[n][h]
__global__ __launch_bounds__(256) void kB1(const float* __restrict__ partials,
                                           const float* __restrict__ b0,
                                           float* __restrict__ hb) {
  const int n  = blockIdx.x >> 3;
  const int hc = blockIdx.x & 7;
  const int tid = threadIdx.x;
  const int hl = tid & 31;
  const int bsub = tid >> 5;     // 8 sub-reducers x 200 each
  const int h = hc * 32 + hl;
  float s = 0.0f;
  for (int j = 0; j < 200; ++j) {
    int b = bsub * 200 + j;
    s += partials[((size_t)(b * Nn + n) << 8) + h];
  }
  __shared__ float red[8][32];
  red[bsub][hl] = s;
  __syncthreads();
  if (tid < 32) {
    float tot = 0.0f;
    #pragma unroll
    for (int sI = 0; sI < 8; ++sI) tot += red[sI][tid];
    int hh = hc * 32 + tid;
    hb[n * Hh + hh] = elu1(tot + b0[hh]);
  }
}

// ---------------- Kernel B2: h2 = elu(hb@W1+b1); logits = h2@W2+b2; softmax -> wgt[n][e]
__global__ __launch_bounds__(256) void kB2(const float* __restrict__ hb,
                                           const float* __restrict__ W1,
                                           const float* __restrict__ b1,
                                           const float* __restrict__ W2,
                                           const float* __restrict__ b2,
                                           float* __restrict__ wgt) {
  const int n = blockIdx.x;
  const int tid = threadIdx.x;
  __shared__ float hbs[Hh];
  hbs[tid] = hb[n * Hh + tid];
  __syncthreads();
  float s = b1[tid];
  for (int j = 0; j < Hh; ++j) s = fmaf(hbs[j], W1[j * Hh + tid], s);
  float h2 = elu1(s);
  float le[Ee];
  #pragma unroll
  for (int e = 0; e < Ee; ++e) le[e] = h2 * W2[tid * Ee + e];
  __shared__ float red[Ee][4];
  const int lane = tid & 63;
  const int wid  = tid >> 6;
  #pragma unroll
  for (int e = 0; e < Ee; ++e) {
    float v = le[e];
    for (int off = 32; off > 0; off >>= 1) v += __shfl_down(v, off, 64);
    if (lane == 0) red[e][wid] = v;
  }
  __syncthreads();
  if (tid == 0) {
    float lg[Ee];
    float m = -1e30f;
    #pragma unroll
    for (int e = 0; e < Ee; ++e) {
      lg[e] = red[e][0] + red[e][1] + red[e][2] + red[e][3] + b2[e];
      m = fmaxf(m, lg[e]);
    }
    float den = 0.0f;
    #pragma unroll
    for (int e = 0; e < Ee; ++e) { lg[e] = expf(lg[e] - m); den += lg[e]; }
    float inv = 1.0f / den;
    #pragma unroll
    for (int e = 0; e < Ee; ++e) wgt[n * Ee + e] = lg[e] * inv;
  }
}

// ---------------- Kernel C: per (n,t): AS[v][w] = sum_e wgt[n][e]*A[e][t][v][w];
//                  out[n][c][t][w] = sum_v x[n][c][t][v] * AS[v][w]
#define ASW 28   // padded AS row
#define XTS 68   // padded xT row
__global__ __launch_bounds__(256) void kC(const float* __restrict__ x,
                                          const float* __restrict__ A,
                                          const float* __restrict__ wgt,
                                          float* __restrict__ out) {
  const int blk = blockIdx.x;
  const int n  = blk >> 6;       // 32 n
  const int tp = blk & 63;       // 64 t-pairs
  const int tid = threadIdx.x;
  const int tsub = tid >> 7;     // which t of the pair
  const int tl = tid & 127;
  const int t = tp * 2 + tsub;

  __shared__ float AS[2][Vv][ASW];
  __shared__ float xT[2][Vv][XTS];

  float wv[Ee];
  #pragma unroll
  for (int e = 0; e < Ee; ++e) wv[e] = wgt[n * Ee + e];

  for (int idx = tl; idx < Vv * ASW; idx += 128) {
    int v = idx / ASW;
    int w = idx - v * ASW;
    float s = 0.0f;
    if (w < Vv) {
      #pragma unroll
      for (int e = 0; e < Ee; ++e)
        s = fmaf(wv[e], A[((size_t)(e * Tt + t) * Vv + v) * Vv + w], s);
    }
    AS[tsub][v][w] = s;
  }
  const float* xb = x + (size_t)n * (Cc * Tt * Vv) + (size_t)t * Vv;
  for (int idx = tl; idx < Cc * Vv; idx += 128) {
    int c = idx / Vv;
    int v = idx - c * Vv;
    xT[tsub][v][c] = xb[(size_t)c * (Tt * Vv) + v];
  }
  __syncthreads();

  const int ct = tl & 15;        // c0 = ct*4
  const int wq = tl >> 4;        // 0..7, active if <7
  if (wq < 7) {
    const int c0 = ct * 4;
    const int w0 = wq * 4;
    float acc[4][4];
    #pragma unroll
    for (int i = 0; i < 4; ++i)
      #pragma unroll
      for (int j = 0; j < 4; ++j) acc[i][j] = 0.0f;
    #pragma unroll 5
    for (int v = 0; v < Vv; ++v) {
      float4 a4 = *(const float4*)&AS[tsub][v][w0];
      float4 x4 = *(const float4*)&xT[tsub][v][c0];
      const float xr[4] = {x4.x, x4.y, x4.z, x4.w};
      const float ar[4] = {a4.x, a4.y, a4.z, a4.w};
      #pragma unroll
      for (int i = 0; i < 4; ++i)
        #pragma unroll
        for (int j = 0; j < 4; ++j)
          acc[i][j] = fmaf(xr[i], ar[j], acc[i][j]);
    }
    #pragma unroll
    for (int i = 0; i < 4; ++i) {
      int c = c0 + i;
      float* ob = out + ((size_t)(n * Cc + c) * Tt + t) * Vv;
      #pragma unroll
      for (int j = 0; j < 4; ++j) {
        int w = w0 + j;
        if (w < Vv) ob[w] = acc[i][j];
      }
    }
  }
}

extern "C" void kernel_launch(void* const* d_in, const int* in_sizes, int n_in,
                              void* d_out, int out_size, void* d_ws, size_t ws_size,
                              hipStream_t stream) {
  const float* x  = (const float*)d_in[0];
  const float* W0 = (const float*)d_in[1];
  const float* b0 = (const float*)d_in[2];
  const float* W1 = (const float*)d_in[3];
  const float* b1 = (const float*)d_in[4];
  const float* W2 = (const float*)d_in[5];
  const float* b2 = (const float*)d_in[6];
  const float* A  = (const float*)d_in[7];
  float* out = (float*)d_out;

  float* partials = (float*)d_ws;                          // 1600*32*256 floats = 52.4 MB
  float* hb  = partials + (size_t)NBLK_A * Nn * Hh;        // 8192 floats
  float* wgt = hb + Nn * Hh;                               // 128 floats

  kA <<<NBLK_A,  256, 0, stream>>>(x, W0, partials);
  kB1<<<256,     256, 0, stream>>>(partials, b0, hb);
  kB2<<<Nn,      256, 0, stream>>>(hb, W1, b1, W2, b2, wgt);
  kC <<<Nn * 64, 256, 0, stream>>>(x, A, wgt, out);
}